// Round 9
// baseline (80.223 us; speedup 1.0000x reference)
//
#include <hip/hip_runtime.h>

#define BB 8
#define CC 256
#define HH 96
#define WW 96
#define HWW (HH*WW)
#define NLOC 256        // local prototypes (MFMA path)
#define PPAD 257        // + global prototype
#define THRESH 0.95f
#define NORM_EPS 1e-4f

typedef __attribute__((ext_vector_type(8))) _Float16 f16x8;
typedef __attribute__((ext_vector_type(4))) float f32x4;

union H16 { _Float16 f; unsigned short u; };
union V8  { f16x8 v; uint4 q; unsigned short us[8]; };

// ---- fused kernel 0+1: mask pooling (8 blocks) + feature pooling (2048) ----
__global__ void k01(const float* __restrict__ sup_fts,
                    const float* __restrict__ sup_mask,
                    const float* __restrict__ true_bg,
                    float* __restrict__ protos,
                    float* __restrict__ validf,
                    float* __restrict__ masksum) {
    __shared__ float red[256];
    int blk = blockIdx.x;
    int t = threadIdx.x;
    if (blk < BB * CC) {
        int b = blk >> 8, c = blk & 255;
        int gy = t >> 4, gx = t & 15;
        const float* fb = sup_fts + ((size_t)b * CC + c) * HWW;
        const float* mb = sup_mask + (size_t)b * HWW;
        int base = gy * 6 * WW + gx * 6;
        float fs = 0.f, fm = 0.f;
        for (int r = 0; r < 6; ++r) {
            const float* rowf = fb + base + r * WW;
            const float* rowm = mb + base + r * WW;
#pragma unroll
            for (int h = 0; h < 3; ++h) {
                float2 v  = *(const float2*)(rowf + 2 * h);
                float2 mk = *(const float2*)(rowm + 2 * h);
                fs += v.x + v.y;
                fm = fmaf(v.x, mk.x, fm);
                fm = fmaf(v.y, mk.y, fm);
            }
        }
        protos[((size_t)b * PPAD + t) * CC + c] = fs * (1.f / 36.f);
        red[t] = fm;
        __syncthreads();
        for (int off = 128; off > 0; off >>= 1) {
            if (t < off) red[t] += red[t + off];
            __syncthreads();
        }
        if (t == 0) protos[((size_t)b * PPAD + 256) * CC + c] = red[0];
    } else {
        int b = blk - BB * CC;
        int gy = t >> 4, gx = t & 15;
        const float* mb = sup_mask + (size_t)b * HWW;
        const float* gb = true_bg  + (size_t)b * HWW;
        int base = gy * 6 * WW + gx * 6;
        float ms = 0.f, bs = 0.f;
        for (int r = 0; r < 6; ++r) {
            const float* rowm = mb + base + r * WW;
            const float* rowg = gb + base + r * WW;
#pragma unroll
            for (int h = 0; h < 3; ++h) {
                float2 mk = *(const float2*)(rowm + 2 * h);
                float2 bg2 = *(const float2*)(rowg + 2 * h);
                ms += mk.x + mk.y;
                bs += bg2.x + bg2.y;
            }
        }
        float mmean = ms * (1.f / 36.f);
        float bmean = bs * (1.f / 36.f);
        validf[b * PPAD + t] = (mmean > THRESH && bmean < 0.5f) ? 1.f : 0.f;
        if (t == 0) validf[b * PPAD + 256] = 1.f;
        red[t] = ms;
        __syncthreads();
        for (int off = 128; off > 0; off >>= 1) {
            if (t < off) red[t] += red[t + off];
            __syncthreads();
        }
        if (t == 0) masksum[b] = red[0];
    }
}

// ------- kernel 2: finish gproto + normalize + emit SINGLE-fp16 P-image -----
// Pimg layout (fp16 bits): [B][8 kc][256 p][32 j]
__global__ void k2_norm(float* __restrict__ protos,
                        const float* __restrict__ masksum,
                        unsigned short* __restrict__ Pimg) {
    int bp = blockIdx.x;
    int b = bp / PPAD;
    int p = bp - b * PPAD;
    int t = threadIdx.x;            // channel
    float v = protos[((size_t)b * PPAD + p) * CC + t];
    if (p == 256) v = v / (masksum[b] + 1e-5f);
    __shared__ float red[256];
    red[t] = v * v;
    __syncthreads();
    for (int off = 128; off > 0; off >>= 1) {
        if (t < off) red[t] += red[t + off];
        __syncthreads();
    }
    float norm = sqrtf(red[0]);
    float vn = v / fmaxf(norm, NORM_EPS);
    protos[((size_t)b * PPAD + p) * CC + t] = vn;
    if (p < NLOC) {
        H16 h; h.f = (_Float16)vn;            // RNE cvt, err 2^-11
        int kc = t >> 5, j = t & 31;
        Pimg[(size_t)(b * 8 + kc) * 8192 + p * 32 + j] = h.u;
    }
}

// ---------------- kernel 3: MFMA dists + masked softmax + weighted sum ------
// 1-wave blocks (64 thr), 32 px x all 257 protos. ZERO barriers.
// Prologue: load q (32KB, the only HBM stream) once, exact fp16 hi/lo split,
// store to PRIVATE swizzled LDS; fp32 |q|^2 + gproto dot ride along.
// K-loop: ds_read Q-frags (conflict-free via XOR swizzle) + ONE vmem stream
// (protos, fp16, 2MB/batch -> L2-resident on every XCD) with 8-deep register
// lookahead + 2 MFMAs per tile (q = qh + ql exact; proto single fp16).
// No cross-stream vmcnt entanglement, no barrier drains, waves independent.
__global__ __launch_bounds__(64)
void k3_mfma(const float* __restrict__ qry,
             const unsigned short* __restrict__ Pimg,
             const float* __restrict__ protos_n,
             const float* __restrict__ validf,
             float* __restrict__ out) {
    __shared__ alignas(16) unsigned short Qlds[2][8192];   // 32 KB: [hi/lo][32px*256ch]

    int blk = blockIdx.x;
    int b = blk & 7;                 // batch <-> XCD affinity
    int tile = blk >> 3;             // 0..287
    int t = threadIdx.x;             // 0..63
    int g = t >> 4;                  // k-group
    int n = t & 15;                  // 16-lane frag index
    int px0 = tile * 32;

    int spx = t & 31;                // prologue: pixel owned
    int h   = t >> 5;                // prologue: channel half (0/1)

    const float* qb = qry + (size_t)b * CC * HWW + px0 + spx;
    const float* gp = protos_n + ((size_t)b * PPAD + 256) * CC;
    const unsigned short* Pb = Pimg + (size_t)b * 8 * 8192;
    char* ldsb = (char*)&Qlds[0][0];

    // ---- prologue: q load + exact fp16 hi/lo split + swizzled LDS store ----
    float nrm = 0.f, gac = 0.f;
    for (int cq = 0; cq < 32; ++cq) {            // 4 channels per iter
        int c = h * 128 + cq * 4;
        float v[4];
#pragma unroll
        for (int j = 0; j < 4; ++j) v[j] = qb[(size_t)(c + j) * HWW];
        unsigned int hh[4], ll[4];
#pragma unroll
        for (int j = 0; j < 4; ++j) {
            H16 x; x.f = (_Float16)v[j];                 // hi (RNE)
            float lof = v[j] - (float)x.f;               // exact residual
            H16 y; y.f = (_Float16)lof;                  // lo
            hh[j] = x.u; ll[j] = y.u;
            nrm = fmaf(v[j], v[j], nrm);
            gac = fmaf(v[j], gp[c + j], gac);
        }
        uint2 Hp, Lp;
        Hp.x = hh[0] | (hh[1] << 16); Hp.y = hh[2] | (hh[3] << 16);
        Lp.x = ll[0] | (ll[1] << 16); Lp.y = ll[2] | (ll[3] << 16);
        int local = c * 2;                               // byte offset in row
        int sw = local ^ ((spx & 7) << 4);               // XOR swizzle bits 4-6
        *(uint2*)(ldsb + spx * 512 + sw) = Hp;           // hi plane
        *(uint2*)(ldsb + 16384 + spx * 512 + sw) = Lp;   // lo plane
    }
    // full-wave |q|^2 and gproto-dot (halves in lanes t, t^32)
    float nrm_full = nrm + __shfl_xor(nrm, 32);
    float gac_full = gac + __shfl_xor(gac, 32);

    // ---- accumulators: [px-sub 0..1][proto-tile ct 0..15] ----
    f32x4 acc[2][16];
#pragma unroll
    for (int s = 0; s < 2; ++s)
#pragma unroll
        for (int c2 = 0; c2 < 16; ++c2) acc[s][c2] = (f32x4){0.f, 0.f, 0.f, 0.f};

#define LOADB_(KCI)                                                           \
    (*(const f16x8*)(Pb + (size_t)((KCI) >> 4) * 8192 +                       \
                     (((KCI) & 15) * 16 + n) * 32 + g * 8))

    // ---- main loop: flat 128 steps (8 kc x 16 ct), 8-deep B lookahead ----
    f16x8 Bf[8];
#pragma unroll
    for (int i = 0; i < 8; ++i) Bf[i] = LOADB_(i);
    f16x8 QH[2], QL[2];
#pragma unroll
    for (int kci = 0; kci < 128; ++kci) {
        const int kc = kci >> 4, ct = kci & 15;
        if (ct == 0) {
#pragma unroll
            for (int sub = 0; sub < 2; ++sub) {
                int px = sub * 16 + n;
                int sw = (kc * 64 + g * 16) ^ ((px & 7) << 4);
                QH[sub] = *(const f16x8*)(ldsb + px * 512 + sw);
                QL[sub] = *(const f16x8*)(ldsb + 16384 + px * 512 + sw);
            }
        }
        f16x8 bc = Bf[kci & 7];
        if (kci < 120) Bf[kci & 7] = LOADB_(kci + 8);
        acc[0][ct] = __builtin_amdgcn_mfma_f32_16x16x32_f16(QH[0], bc, acc[0][ct], 0, 0, 0);
        acc[0][ct] = __builtin_amdgcn_mfma_f32_16x16x32_f16(QL[0], bc, acc[0][ct], 0, 0, 0);
        acc[1][ct] = __builtin_amdgcn_mfma_f32_16x16x32_f16(QH[1], bc, acc[1][ct], 0, 0, 0);
        acc[1][ct] = __builtin_amdgcn_mfma_f32_16x16x32_f16(QL[1], bc, acc[1][ct], 0, 0, 0);
    }
#undef LOADB_

    // ---- per-row rnorm / global-proto dist via shuffles (no LDS, no bar) ---
    // D-map: col(proto) = n (+16ct), row(px) = sub*16 + 4g + r.
    float rnorm[2][4], gd[2][4];
#pragma unroll
    for (int sub = 0; sub < 2; ++sub)
#pragma unroll
        for (int r = 0; r < 4; ++r) {
            int px = sub * 16 + 4 * g + r;
            float n2 = __shfl(nrm_full, px);     // lane px holds norm2[px]
            float gs = __shfl(gac_full, px);
            float rn = 1.f / fmaxf(sqrtf(n2), NORM_EPS);
            rnorm[sub][r] = rn;
            gd[sub][r] = gs * rn;
        }

    // valid flags for this lane's proto column across the 16 tiles
    float vf[16];
    const float* vb = validf + b * PPAD;
#pragma unroll
    for (int ct = 0; ct < 16; ++ct) vf[ct] = vb[ct * 16 + n];

    // ---- softmax (fixed shift 1.1) + weighted sum; gproto added ONCE ----
#pragma unroll
    for (int sub = 0; sub < 2; ++sub) {
        float S[4] = {0.f, 0.f, 0.f, 0.f};
        float NN[4] = {0.f, 0.f, 0.f, 0.f};
#pragma unroll
        for (int ct = 0; ct < 16; ++ct) {
#pragma unroll
            for (int r = 0; r < 4; ++r) {
                float d = acc[sub][ct][r] * rnorm[sub][r];
                float l = (vf[ct] != 0.f) ? d : -1e30f;
                float e = __expf(l - 1.1f);      // masked -> exactly 0
                S[r] += e;
                NN[r] = fmaf(e, l, NN[r]);
            }
        }
#pragma unroll
        for (int r = 0; r < 4; ++r) {
#pragma unroll
            for (int m = 1; m < 16; m <<= 1) {
                S[r]  += __shfl_xor(S[r], m);
                NN[r] += __shfl_xor(NN[r], m);
            }
            float eg = __expf(gd[sub][r] - 1.1f);
            S[r] += eg;
            NN[r] = fmaf(eg, gd[sub][r], NN[r]);
        }
        if (n < 4) {   // lane (g, n<4) writes row 4g+n, slot r=n
            float Ssel = (n == 0) ? S[0] : (n == 1) ? S[1] : (n == 2) ? S[2] : S[3];
            float Nsel = (n == 0) ? NN[0] : (n == 1) ? NN[1] : (n == 2) ? NN[2] : NN[3];
            out[(size_t)b * HWW + px0 + sub * 16 + 4 * g + n] = Nsel / Ssel;
        }
    }
}

extern "C" void kernel_launch(void* const* d_in, const int* in_sizes, int n_in,
                              void* d_out, int out_size, void* d_ws, size_t ws_size,
                              hipStream_t stream) {
    const float* qry = (const float*)d_in[0];
    const float* sup = (const float*)d_in[1];
    const float* msk = (const float*)d_in[2];
    const float* bg  = (const float*)d_in[3];
    float* out = (float*)d_out;

    float* ws = (float*)d_ws;
    float* protos  = ws;                                   // [B][257][256] f32
    float* validf  = protos + (size_t)BB * PPAD * CC;      // [B][257]
    float* masksum = validf + (size_t)BB * PPAD;           // [B]
    unsigned short* Pimg = (unsigned short*)(masksum + BB); // [B][8][256][32] fp16 bits

    hipLaunchKernelGGL(k01, dim3(BB * CC + BB), dim3(256), 0, stream,
                       sup, msk, bg, protos, validf, masksum);
    hipLaunchKernelGGL(k2_norm, dim3(BB * PPAD), dim3(256), 0, stream, protos, masksum, Pimg);
    hipLaunchKernelGGL(k3_mfma, dim3(BB * (HWW / 32)), dim3(64), 0, stream,
                       qry, Pimg, protos, validf, out);
}